// Round 1
// baseline (144654.529 us; speedup 1.0000x reference)
//
#include <hip/hip_runtime.h>
#include <stdint.h>

#define S_LEN 8192
#define HID   1024
#define DIN0  256
#define NCU_L 64     // CUs per layer
#define NL    4

typedef _Float16 half2v __attribute__((ext_vector_type(2)));

#if defined(__has_builtin)
#if __has_builtin(__builtin_amdgcn_fdot2)
#define HAVE_FDOT2 1
#endif
#endif

__device__ __forceinline__ float dot2acc(uint32_t w, uint32_t x, float acc) {
#ifdef HAVE_FDOT2
    return __builtin_amdgcn_fdot2(__builtin_bit_cast(half2v, w),
                                  __builtin_bit_cast(half2v, x), acc, false);
#else
    half2v hw = __builtin_bit_cast(half2v, w);
    half2v hx = __builtin_bit_cast(half2v, x);
    return acc + (float)hw.x * (float)hx.x + (float)hw.y * (float)hx.y;
#endif
}

// ---- workspace layout (bytes) ----
// x0 packed fp16 pairs:  S*DIN0*2          = 4 MB
// h_hist fp16:           NL*S*H*2          = 64 MB
// wpack dwords:          (160 + 3*256)*16384*4 = ~58 MB
// counters: NL*S ints + abort flag
constexpr size_t X0_DW  = (size_t)S_LEN * DIN0 / 2;          // dwords
constexpr size_t X0B    = X0_DW * 4;
constexpr size_t HB     = (size_t)NL * S_LEN * HID * 2;
constexpr size_t L0W_DW = (size_t)160 * 16384;               // dwords
constexpr size_t LW_DW  = (size_t)256 * 16384;
constexpr size_t WB     = (L0W_DW + 3 * LW_DW) * 4;
constexpr size_t CNT_N  = (size_t)NL * S_LEN + 1;            // +1 abort flag
constexpr size_t TOTAL_WS = X0B + HB + WB + CNT_N * 4;

// ---------------- pre-kernels ----------------

__global__ void conv_x_kernel(const float* __restrict__ x, uint32_t* __restrict__ dst) {
    int i = blockIdx.x * 256 + threadIdx.x;   // exactly S*DIN0/2 threads
    float v0 = x[2 * i], v1 = x[2 * i + 1];
    half2v h = {(_Float16)v0, (_Float16)v1};
    dst[i] = __builtin_bit_cast(uint32_t, h);
}

__global__ void pack_weights_kernel(const float* __restrict__ wih, const float* __restrict__ whh,
                                    int din, int SP, uint32_t* __restrict__ dst) {
    int i = blockIdx.x * 256 + threadIdx.x;   // exactly 16384*SP threads
    int r = i & 63;
    int rest = i >> 6;
    int c = rest % SP; rest /= SP;
    int w = rest & 3;
    int k = rest >> 2;
    int row = (r >> 4) * HID + k * 16 + (r & 15);
    int col = w * (2 * SP) + 2 * c;
    float v0 = (col < din) ? wih[(size_t)row * din + col] : whh[(size_t)row * HID + (col - din)];
    float v1 = (col + 1 < din) ? wih[(size_t)row * din + col + 1] : whh[(size_t)row * HID + (col + 1 - din)];
    half2v h = {(_Float16)v0, (_Float16)v1};
    dst[i] = __builtin_bit_cast(uint32_t, h);
}

__global__ void init_misc_kernel(int* __restrict__ cnt, int n, float* __restrict__ out,
                                 const float* __restrict__ fcb) {
    int i = blockIdx.x * 256 + threadIdx.x;
    if (i < n) cnt[i] = 0;
    if (i == 0) out[0] = fcb[0];
}

// ---------------- persistent LSTM kernel ----------------

__device__ __forceinline__ void wait_ge64(int* p, int* abortf) {
    int it = 0;
    while (__hip_atomic_load(p, __ATOMIC_RELAXED, __HIP_MEMORY_SCOPE_AGENT) < NCU_L) {
        if ((++it & 255) == 0) {
            if (__hip_atomic_load(abortf, __ATOMIC_RELAXED, __HIP_MEMORY_SCOPE_AGENT)) return;
            if (it > (1 << 22)) {
                __hip_atomic_store(abortf, 1, __ATOMIC_RELAXED, __HIP_MEMORY_SCOPE_AGENT);
                return;
            }
        }
    }
}

__device__ __forceinline__ float fsigmoid(float x) {
    return 1.f / (1.f + __expf(-x));
}
__device__ __forceinline__ float ftanh_c(float x) {  // input pre-clamped to |x|<=15
    float e = __expf(-2.f * x);
    return (1.f - e) / (1.f + e);
}

template <int SP, int DIN>
__device__ __forceinline__ void run_layer(
    int k,
    const uint32_t* __restrict__ xsrc,       // packed fp16 pairs, row stride DIN/2 dwords
    _Float16* __restrict__ hh_own,           // own-layer h history (half), row stride HID
    const uint32_t* __restrict__ hh_dw_own,  // same buffer, dword view
    const uint32_t* __restrict__ wsrc,       // this block's packed weights
    const float* __restrict__ bias,
    const float* __restrict__ fcw,
    float* __restrict__ out,
    int* cnt_own, int* cnt_up, int* abortf, bool doFC)
{
    __shared__ alignas(16) uint32_t in_lds[(DIN + HID) / 2];
    __shared__ float red[4][64];

    const int tid = threadIdx.x;
    const int wave = tid >> 6;
    const int lane = tid & 63;

    // --- load this thread's weight slice into registers (stays resident) ---
    uint32_t wreg[SP];
    {
        const uint32_t* wb = wsrc + wave * SP * 64 + lane;
#pragma unroll
        for (int c = 0; c < SP; ++c) wreg[c] = wb[c * 64];
    }

    float bval = 0.f, fcv = 0.f;
    if (wave == 0) {
        bval = bias[(lane >> 4) * HID + k * 16 + (lane & 15)];
        if (lane < 16) fcv = fcw[k * 16 + lane];
    }
    float cst = 0.f, hval = 0.f;

    for (int t = 0; t < S_LEN; ++t) {
        // --- wait for inputs ---
        if (cnt_up) wait_ge64(cnt_up + t, abortf);
        if (t) wait_ge64(cnt_own + t - 1, abortf);
        __builtin_amdgcn_fence(__ATOMIC_ACQUIRE, "agent");

        // --- stage x_t || h_{t-1} into LDS (packed fp16 pairs) ---
        constexpr int XQ = DIN / 8;  // 16B chunks of x part
        if (tid < XQ) {
            ((int4*)in_lds)[tid] = ((const int4*)(xsrc + (size_t)t * (DIN / 2)))[tid];
        } else if (tid < XQ + 128) {
            const int i = tid - XQ;
            int4 v = {0, 0, 0, 0};
            if (t) v = ((const int4*)(hh_dw_own + (size_t)(t - 1) * (HID / 2)))[i];
            ((int4*)in_lds)[XQ + i] = v;
        }
        __syncthreads();

        // --- dot: each lane = one gate row, each wave = one column slice ---
        const uint32_t* wi = in_lds + wave * SP;
        float a0 = 0, a1 = 0, a2 = 0, a3 = 0, a4 = 0, a5 = 0, a6 = 0, a7 = 0;
#pragma unroll
        for (int c = 0; c < SP; c += 8) {
            a0 = dot2acc(wreg[c + 0], wi[c + 0], a0);
            a1 = dot2acc(wreg[c + 1], wi[c + 1], a1);
            a2 = dot2acc(wreg[c + 2], wi[c + 2], a2);
            a3 = dot2acc(wreg[c + 3], wi[c + 3], a3);
            a4 = dot2acc(wreg[c + 4], wi[c + 4], a4);
            a5 = dot2acc(wreg[c + 5], wi[c + 5], a5);
            a6 = dot2acc(wreg[c + 6], wi[c + 6], a6);
            a7 = dot2acc(wreg[c + 7], wi[c + 7], a7);
        }
        red[wave][lane] = ((a0 + a1) + (a2 + a3)) + ((a4 + a5) + (a6 + a7));
        __syncthreads();

        // --- wave 0: reduce, gates, state update, publish ---
        if (wave == 0) {
            float p = red[0][lane] + red[1][lane] + red[2][lane] + red[3][lane] + bval;
            p = fminf(15.f, fmaxf(-15.f, p));
            const int j = lane & 15;
            float pi = __shfl(p, j);
            float pf = __shfl(p, j + 16);
            float pg = __shfl(p, j + 32);
            float po = __shfl(p, j + 48);
            if (lane < 16) {
                float ig = fsigmoid(pi);
                float fg = fsigmoid(pf);
                float gg = ftanh_c(pg);
                float og = fsigmoid(po);
                cst = fg * cst + ig * gg;
                float c2 = fminf(15.f, fmaxf(-15.f, cst));
                hval = og * ftanh_c(c2);
                hh_own[(size_t)t * HID + k * 16 + lane] = (_Float16)hval;
            }
            __builtin_amdgcn_fence(__ATOMIC_RELEASE, "agent");
            if (lane == 0)
                __hip_atomic_fetch_add(cnt_own + t, 1, __ATOMIC_RELAXED, __HIP_MEMORY_SCOPE_AGENT);
        }
    }

    // --- final FC (layer 3 only): y = fc_w . h_last + fc_b ---
    if (doFC && wave == 0) {
        float p = (lane < 16) ? fcv * hval : 0.f;
#pragma unroll
        for (int o = 8; o; o >>= 1) p += __shfl_xor(p, o);
        if (lane == 0) atomicAdd(out, p);
    }
}

__global__ __launch_bounds__(256, 1) void lstm_persistent(
    const uint32_t* __restrict__ x0p,
    _Float16* __restrict__ hh,
    const uint32_t* __restrict__ wp,
    const float* __restrict__ b0, const float* __restrict__ b1,
    const float* __restrict__ b2, const float* __restrict__ b3,
    const float* __restrict__ fcw, float* __restrict__ out,
    int* cnt, int* abortf)
{
    const int bid = blockIdx.x;
    const int xcd = bid & 7;
    const int layer = xcd >> 1;                       // 2 XCDs per layer
    const int k = ((bid >> 3) << 1) | (xcd & 1);      // 0..63 within layer

    const float* bias = (layer == 0) ? b0 : (layer == 1) ? b1 : (layer == 2) ? b2 : b3;
    int* cnt_own = cnt + layer * S_LEN;
    int* cnt_up = layer ? (cnt + (layer - 1) * S_LEN) : nullptr;

    _Float16* hh_own = hh + (size_t)layer * S_LEN * HID;
    const uint32_t* hh_dw_own = (const uint32_t*)hh + (size_t)layer * S_LEN * (HID / 2);

    if (layer == 0) {
        const uint32_t* wsrc = wp + (size_t)k * 160 * 256;
        run_layer<160, DIN0>(k, x0p, hh_own, hh_dw_own, wsrc, bias, fcw, out,
                             cnt_own, nullptr, abortf, false);
    } else {
        const size_t loff = L0W_DW + (size_t)(layer - 1) * LW_DW;
        const uint32_t* xsrc = (const uint32_t*)hh + (size_t)(layer - 1) * S_LEN * (HID / 2);
        const uint32_t* wsrc = wp + loff + (size_t)k * 256 * 256;
        run_layer<256, HID>(k, xsrc, hh_own, hh_dw_own, wsrc, bias, fcw, out,
                            cnt_own, cnt_up, abortf, layer == 3);
    }
}

// ---------------- host launcher ----------------

extern "C" void kernel_launch(void* const* d_in, const int* in_sizes, int n_in,
                              void* d_out, int out_size, void* d_ws, size_t ws_size,
                              hipStream_t stream) {
    const float* seq  = (const float*)d_in[0];
    const float* wih0 = (const float*)d_in[1];
    const float* whh0 = (const float*)d_in[2];
    const float* b0   = (const float*)d_in[3];
    const float* wih1 = (const float*)d_in[4];
    const float* whh1 = (const float*)d_in[5];
    const float* b1   = (const float*)d_in[6];
    const float* wih2 = (const float*)d_in[7];
    const float* whh2 = (const float*)d_in[8];
    const float* b2   = (const float*)d_in[9];
    const float* wih3 = (const float*)d_in[10];
    const float* whh3 = (const float*)d_in[11];
    const float* b3   = (const float*)d_in[12];
    const float* fcw  = (const float*)d_in[13];
    const float* fcb  = (const float*)d_in[14];
    float* out = (float*)d_out;

    if (ws_size < TOTAL_WS) return;  // workspace too small; fail loudly via absmax

    uint8_t* ws = (uint8_t*)d_ws;
    uint32_t* x0p = (uint32_t*)ws;
    _Float16* hh  = (_Float16*)(ws + X0B);
    uint32_t* wp  = (uint32_t*)(ws + X0B + HB);
    int* cnt      = (int*)(ws + X0B + HB + WB);
    int* abortf   = cnt + NL * S_LEN;

    // x -> packed fp16 pairs
    conv_x_kernel<<<(int)(X0_DW / 256), 256, 0, stream>>>(seq, x0p);
    // weights -> per-lane register order, fp16 pairs
    pack_weights_kernel<<<64 * 160, 256, 0, stream>>>(wih0, whh0, DIN0, 160, wp);
    pack_weights_kernel<<<64 * 256, 256, 0, stream>>>(wih1, whh1, HID, 256, wp + L0W_DW);
    pack_weights_kernel<<<64 * 256, 256, 0, stream>>>(wih2, whh2, HID, 256, wp + L0W_DW + LW_DW);
    pack_weights_kernel<<<64 * 256, 256, 0, stream>>>(wih3, whh3, HID, 256, wp + L0W_DW + 2 * LW_DW);
    // counters + abort + out=fc_b
    init_misc_kernel<<<(int)((CNT_N + 255) / 256), 256, 0, stream>>>(cnt, (int)CNT_N, out, fcb);

    // persistent pipelined recurrence: 256 blocks, 1 per CU (VGPR-forced residency)
    lstm_persistent<<<256, 256, 0, stream>>>(x0p, hh, wp, b0, b1, b2, b3, fcw, out, cnt, abortf);
}